// Round 4
// baseline (110.911 us; speedup 1.0000x reference)
//
#include <hip/hip_runtime.h>
#include <math.h>

// Problem constants
#define BB 32
#define PP 2048
#define DD 768
#define TT 3
#define OO 128
#define HH 192
#define CC 32              // chunks of P per batch for the streaming kernel
#define ROWS (PP / CC)     // 64 rows per block
#define SCALE 0.03608439182435161f  // 1/sqrt(768)

// ---------------------------------------------------------------------------
// K1a: q[t,e] = sum_d tt[t,d]*Wq[t,d,e] + bq[t,e] — W-read-once, K-split 16.
// grid = T*48 (e-chunks of 16), block 256 = 16 e * 16 k-groups.
// ---------------------------------------------------------------------------
__global__ void k_q(const float* __restrict__ tt, const float* __restrict__ Wq,
                    const float* __restrict__ bq, float* __restrict__ q) {
    __shared__ float red[16][16];
    int t = blockIdx.x / 48, ec = blockIdx.x % 48;
    int tid = threadIdx.x;
    int le = tid & 15, kg = tid >> 4;
    int e = ec * 16 + le;
    const float* w  = Wq + (size_t)t * DD * DD + e;
    const float* tr = tt + t * DD;
    float a = 0.f;
#pragma unroll 4
    for (int d = kg * 48; d < kg * 48 + 48; ++d)
        a += tr[d] * w[(size_t)d * DD];
    red[kg][le] = a;
    __syncthreads();
    if (kg == 0) {
        float s = bq[t * DD + e];
#pragma unroll
        for (int i = 0; i < 16; ++i) s += red[i][le];
        q[t * DD + e] = s;
    }
}

// ---------------------------------------------------------------------------
// K1b: kq[t,d] = SCALE * sum_e Wk[t,d,e] * q[t,e]   (row-contiguous matvec)
// grid 576 = T*192, one wave per d (4 waves/block)
// ---------------------------------------------------------------------------
__global__ void k_kq(const float* __restrict__ Wk, const float* __restrict__ q,
                     float* __restrict__ kq) {
    int t = blockIdx.x / 192;
    int d = (blockIdx.x % 192) * 4 + (threadIdx.x >> 6);
    int L = threadIdx.x & 63;
    const float4* wr = (const float4*)(Wk + (size_t)(t * DD + d) * DD);
    const float4* qr = (const float4*)(q + t * DD);
    float s = 0.f;
#pragma unroll
    for (int g = 0; g < 3; ++g) {
        float4 a = wr[g * 64 + L], b = qr[g * 64 + L];
        s += a.x * b.x + a.y * b.y + a.z * b.z + a.w * b.w;
    }
#pragma unroll
    for (int off = 32; off; off >>= 1) s += __shfl_xor(s, off);
    if (L == 0) kq[t * DD + d] = s * SCALE;
}

// ---------------------------------------------------------------------------
// K2 main stream (unchanged control): per x-row (skip masked):
//   s[t] = x_row . kq[t]; e = exp(s); l[t] += e; acc[t] += e * x_row.
// grid 1024 = B*32 blocks, 256 threads (4 waves, 16 rows each).
// ---------------------------------------------------------------------------
__global__ __launch_bounds__(256, 4) void k_main(const float* __restrict__ x,
        const int* __restrict__ mask, const float* __restrict__ kq,
        float* __restrict__ xap, float* __restrict__ lp) {
    __shared__ float red[4][TT * DD];   // 36 KB; red[0..] doubles as kq stage
    __shared__ float redl[4][TT];
    int bid = blockIdx.x;
    int b = bid >> 5, c = bid & 31;
    int tid = threadIdx.x, w = tid >> 6, L = tid & 63;

    float* kqs = &red[0][0];
#pragma unroll
    for (int k2 = 0; k2 < 9; ++k2) kqs[tid + k2 * 256] = kq[tid + k2 * 256];
    __syncthreads();
    const float4* kq4 = (const float4*)kqs;

    float4 acc[TT][3] = {};
    float l[TT] = {0.f, 0.f, 0.f};
    const float* xb = x + (size_t)b * PP * DD;
    const int* mb = mask + b * PP;
    int p0 = c * ROWS + w * (ROWS / 4);

    for (int r = 0; r < ROWS / 4; ++r) {
        int p = p0 + r;
        if (mb[p]) continue;
        const float4* xr = (const float4*)(xb + (size_t)p * DD);
        float4 xv[3];
#pragma unroll
        for (int g = 0; g < 3; ++g) xv[g] = xr[g * 64 + L];
        float s[TT];
#pragma unroll
        for (int t = 0; t < TT; ++t) {
            float a = 0.f;
#pragma unroll
            for (int g = 0; g < 3; ++g) {
                float4 kf = kq4[t * 192 + g * 64 + L];
                a += xv[g].x * kf.x + xv[g].y * kf.y
                   + xv[g].z * kf.z + xv[g].w * kf.w;
            }
            s[t] = a;
        }
#pragma unroll
        for (int off = 32; off; off >>= 1) {
            s[0] += __shfl_xor(s[0], off);
            s[1] += __shfl_xor(s[1], off);
            s[2] += __shfl_xor(s[2], off);
        }
#pragma unroll
        for (int t = 0; t < TT; ++t) {
            float e = expf(s[t]);
            l[t] += e;
#pragma unroll
            for (int g = 0; g < 3; ++g) {
                acc[t][g].x += e * xv[g].x;
                acc[t][g].y += e * xv[g].y;
                acc[t][g].z += e * xv[g].z;
                acc[t][g].w += e * xv[g].w;
            }
        }
    }

    __syncthreads();
#pragma unroll
    for (int t = 0; t < TT; ++t)
#pragma unroll
        for (int g = 0; g < 3; ++g)
            *(float4*)&red[w][t * DD + g * 256 + 4 * L] = acc[t][g];
    if (L == 0) {
#pragma unroll
        for (int t = 0; t < TT; ++t) redl[w][t] = l[t];
    }
    __syncthreads();

    float* outp = xap + (size_t)bid * (TT * DD);
#pragma unroll
    for (int k = 0; k < 9; ++k) {
        int i = tid + k * 256;
        outp[i] = red[0][i] + red[1][i] + red[2][i] + red[3][i];
    }
    if (tid < TT)
        lp[bid * TT + tid] = redl[0][tid] + redl[1][tid] + redl[2][tid] + redl[3][tid];
}

// ---------------------------------------------------------------------------
// K3: combine chunk partials:  xa[t,b,d] = (sum_c xap) / (sum_c lp)
// ---------------------------------------------------------------------------
__global__ void k_comb(const float* __restrict__ xap, const float* __restrict__ lp,
                       float* __restrict__ xa) {
    int t = blockIdx.x >> 5, b = blockIdx.x & 31;
    int tid = threadIdx.x;
    float lsum = 0.f;
#pragma unroll
    for (int c = 0; c < CC; ++c) lsum += lp[(b * CC + c) * TT + t];
    float inv = 1.0f / lsum;
#pragma unroll
    for (int k = 0; k < 3; ++k) {
        int d = tid + k * 256;
        float s = 0.f;
#pragma unroll
        for (int c = 0; c < CC; ++c)
            s += xap[(size_t)(b * CC + c) * (TT * DD) + t * DD + d];
        xa[(t * BB + b) * DD + d] = s * inv;
    }
}

// ---------------------------------------------------------------------------
// P1: W-stationary split-K partial GEMM.
// part[t,kc,b,e] = sum_{kk} in[t,b,kc*KCH+kk] * W[t,kc*KCH+kk,e]
// grid = T*KC*(N/64), block 256 = 64 e-lanes x 4 b-groups (8 b each).
// Each W element read exactly once across the grid.
// ---------------------------------------------------------------------------
template<int K, int N, int KC>
__global__ void k_p1(const float* __restrict__ in, const float* __restrict__ W,
                     float* __restrict__ part) {
    constexpr int KCH = K / KC;
    constexpr int NCH = N / 64;
    __shared__ float ins[BB][KCH];   // 12.3 KB for KCH=96
    int blk = blockIdx.x;
    int t  = blk / (KC * NCH);
    int r  = blk % (KC * NCH);
    int kc = r / NCH;
    int ec = r % NCH;
    int tid = threadIdx.x;

    constexpr int TOT = BB * KCH;
    for (int i = tid; i < TOT; i += 256) {
        int b = i / KCH, kk = i % KCH;
        ins[b][kk] = in[((size_t)t * BB + b) * K + kc * KCH + kk];
    }
    __syncthreads();

    int le = tid & 63, bg = tid >> 6;
    int e = ec * 64 + le;
    const float* wp = W + (size_t)t * K * N + (size_t)(kc * KCH) * N + e;
    float acc[8] = {};
#pragma unroll 4
    for (int kk = 0; kk < KCH; ++kk) {
        float wv = wp[(size_t)kk * N];
#pragma unroll
        for (int j = 0; j < 8; ++j)
            acc[j] += ins[bg * 8 + j][kk] * wv;
    }
#pragma unroll
    for (int j = 0; j < 8; ++j)
        part[(((size_t)t * KC + kc) * BB + (bg * 8 + j)) * N + e] = acc[j];
}

// ---------------------------------------------------------------------------
// P2: reduce KC partials + bias (+tt) (+gelu).  grid = T*BB, block 256.
// ---------------------------------------------------------------------------
template<int N, int KC, bool ADD_TT, bool GELU>
__global__ void k_p2(const float* __restrict__ part, const float* __restrict__ bias,
                     const float* __restrict__ tt, float* __restrict__ out) {
    int t = blockIdx.x / BB, b = blockIdx.x % BB;
    int tid = threadIdx.x;
    for (int e = tid; e < N; e += 256) {
        float s = bias[t * N + e];
        if (ADD_TT) s += tt[t * N + e];
#pragma unroll
        for (int kc = 0; kc < KC; ++kc)
            s += part[(((size_t)t * KC + kc) * BB + b) * N + e];
        if (GELU) s = 0.5f * s * (1.0f + erff(s * 0.70710678118654752f));
        out[((size_t)t * BB + b) * N + e] = s;
    }
}

// ---------------------------------------------------------------------------
// Tail: h = gelu(reduce(partH)+h1b) in LDS, then out = h @ h2w + h2b.
// grid = T*BB, block 192 (3 waves).
// ---------------------------------------------------------------------------
__global__ void k_tail(const float* __restrict__ partH, const float* __restrict__ h1b,
                       const float* __restrict__ h2w, const float* __restrict__ h2b,
                       float* __restrict__ out) {
    __shared__ float hl[HH];
    int t = blockIdx.x / BB, b = blockIdx.x % BB;
    int tid = threadIdx.x;
    if (tid < HH) {
        float s = h1b[t * HH + tid];
#pragma unroll
        for (int kc = 0; kc < 8; ++kc)
            s += partH[(((size_t)t * 8 + kc) * BB + b) * HH + tid];
        hl[tid] = 0.5f * s * (1.0f + erff(s * 0.70710678118654752f));
    }
    __syncthreads();
    if (tid < OO) {
        float s = h2b[t * OO + tid];
#pragma unroll 8
        for (int kh = 0; kh < HH; ++kh)
            s += hl[kh] * h2w[((size_t)t * HH + kh) * OO + tid];
        out[((size_t)t * BB + b) * OO + tid] = s;
    }
}

// ---------------------------------------------------------------------------
extern "C" void kernel_launch(void* const* d_in, const int* in_sizes, int n_in,
                              void* d_out, int out_size, void* d_ws, size_t ws_size,
                              hipStream_t stream) {
    const float* x    = (const float*)d_in[0];
    const int*   mask = (const int*)d_in[1];   // True = masked
    const float* tt   = (const float*)d_in[2];
    const float* Wq   = (const float*)d_in[3];
    const float* bq   = (const float*)d_in[4];
    const float* Wk   = (const float*)d_in[5];
    // d_in[6] = bk: unused — adds a per-(t) constant to scores, cancels in softmax
    const float* Wv   = (const float*)d_in[7];
    const float* bv   = (const float*)d_in[8];
    const float* Wo   = (const float*)d_in[9];
    const float* bo   = (const float*)d_in[10];
    const float* h1w  = (const float*)d_in[11];
    const float* h1b  = (const float*)d_in[12];
    const float* h2w  = (const float*)d_in[13];
    const float* h2b  = (const float*)d_in[14];
    float* out = (float*)d_out;

    // workspace layout (floats); total ~16 MB
    float* ws    = (float*)d_ws;
    float* q     = ws;                         // 2304
    float* kq    = q + TT * DD;                // 2304
    float* xap   = kq + TT * DD;               // 1024*2304
    float* lp    = xap + BB * CC * TT * DD;    // 3072
    float* xa    = lp + BB * CC * TT;          // 96*768
    float* partV = xa + TT * BB * DD;          // 3*8*32*768 = 589824
    float* y     = partV + TT * 8 * BB * DD;   // 96*768
    float* partO = y + TT * BB * DD;           // 589824
    float* y2    = partO + TT * 8 * BB * DD;   // 96*768
    float* partH = y2 + TT * BB * DD;          // 3*8*32*192 = 147456

    hipLaunchKernelGGL(k_q,    dim3(TT * 48), dim3(256), 0, stream, tt, Wq, bq, q);
    hipLaunchKernelGGL(k_kq,   dim3(576),     dim3(256), 0, stream, Wk, q, kq);
    hipLaunchKernelGGL(k_main, dim3(BB * CC), dim3(256), 0, stream, x, mask, kq, xap, lp);
    hipLaunchKernelGGL(k_comb, dim3(96),      dim3(256), 0, stream, xap, lp, xa);
    // y = xa @ Wv + bv
    hipLaunchKernelGGL((k_p1<DD, DD, 8>), dim3(TT * 8 * 12), dim3(256), 0, stream, xa, Wv, partV);
    hipLaunchKernelGGL((k_p2<DD, 8, false, false>), dim3(TT * BB), dim3(256), 0, stream, partV, bv, nullptr, y);
    // y2 = y @ Wo + bo + tt
    hipLaunchKernelGGL((k_p1<DD, DD, 8>), dim3(TT * 8 * 12), dim3(256), 0, stream, y, Wo, partO);
    hipLaunchKernelGGL((k_p2<DD, 8, true, false>), dim3(TT * BB), dim3(256), 0, stream, partO, bo, tt, y2);
    // h = gelu(y2 @ h1w + h1b);  out = h @ h2w + h2b
    hipLaunchKernelGGL((k_p1<DD, HH, 8>), dim3(TT * 8 * 3), dim3(256), 0, stream, y2, h1w, partH);
    hipLaunchKernelGGL(k_tail, dim3(TT * BB), dim3(192), 0, stream, partH, h1b, h2w, h2b, out);
}